// Round 10
// baseline (218.018 us; speedup 1.0000x reference)
//
#include <hip/hip_runtime.h>
#include <hip/hip_bf16.h>

#define T_SEQ 4096
#define DIM   256
#define NBATCH 4

typedef short s8v __attribute__((ext_vector_type(8)));   // 8 bf16 (A/B frag)
typedef float f4v __attribute__((ext_vector_type(4)));   // 4 fp32 (C/D frag)
typedef unsigned short u16;

#define MFMA16(a,b,c) __builtin_amdgcn_mfma_f32_16x16x32_bf16(a,b,c,0,0,0)
#define FENCE_LGKM() asm volatile("s_waitcnt lgkmcnt(0)" ::: "memory")

// dynamic task counters, one per batch; zeroed by wtrans_kernel each launch
__device__ int g_cnt[4];

static __device__ __forceinline__ u16 f2bf(float f) {
  union { float f; unsigned int u; } c; c.f = f;
  unsigned int u = c.u;
  unsigned int r = (u + 0x7fffu + ((u >> 16) & 1u)) >> 16;   // RNE
  return (u16)r;
}

static __device__ __forceinline__ s8v pack8(const float* p) {
  float4 a = *(const float4*)p;
  float4 b = *(const float4*)(p + 4);
  s8v r;
  r[0] = (short)f2bf(a.x); r[1] = (short)f2bf(a.y);
  r[2] = (short)f2bf(a.z); r[3] = (short)f2bf(a.w);
  r[4] = (short)f2bf(b.x); r[5] = (short)f2bf(b.y);
  r[6] = (short)f2bf(b.z); r[7] = (short)f2bf(b.w);
  return r;
}

// async global->LDS DMA, 16B/lane: lds dest is WAVE-UNIFORM base (+lane*16 by HW)
static __device__ __forceinline__ void gll16(const u16* g, u16* l) {
  __builtin_amdgcn_global_load_lds(
      (const __attribute__((address_space(1))) unsigned int*)g,
      (__attribute__((address_space(3))) unsigned int*)l, 16, 0, 0);
}

// ---------- diagnostic fallback (fp32 out) ----------
__global__ void diag_fill_kernel(float* __restrict__ out, float val, int n) {
  int i = blockIdx.x * blockDim.x + threadIdx.x;
  if (i < n) out[i] = val;
}

// ---------- kernel 1: Wt[n][k] = bf16(W[k][n]) ----------
__global__ void wtrans_kernel(const float* __restrict__ Wq, const float* __restrict__ Wk,
                              const float* __restrict__ Wv, u16* __restrict__ Wt) {
  if (blockIdx.x == 0 && blockIdx.y == 0 && blockIdx.z == 0 &&
      threadIdx.y == 0 && threadIdx.x < 4)
    g_cnt[threadIdx.x] = 0;                    // reset attn task queues (stream-ordered)
  __shared__ float tile[32][33];
  int m = blockIdx.z;
  const float* W = (m == 0) ? Wq : ((m == 1) ? Wk : Wv);
  int bx = blockIdx.x * 32, by = blockIdx.y * 32;
  int x = threadIdx.x, y = threadIdx.y;          // block (32,8)
  #pragma unroll
  for (int i = 0; i < 32; i += 8) tile[y + i][x] = W[(by + y + i) * DIM + bx + x];
  __syncthreads();
  u16* o = Wt + m * DIM * DIM;
  #pragma unroll
  for (int i = 0; i < 32; i += 8) o[(bx + y + i) * DIM + by + x] = f2bf(tile[x][y + i]);
}

// ---------- kernel 2: Q / K / V projections -> FRAGMENT-MAJOR tiles ------
// (unchanged from r9)
__global__ __launch_bounds__(256) void proj_kernel(
    const float* __restrict__ x, const u16* __restrict__ Wt,
    const float* __restrict__ bq, const float* __restrict__ bk, const float* __restrict__ bv,
    u16* __restrict__ qf, u16* __restrict__ kf, u16* __restrict__ vf) {
  alignas(16) __shared__ u16 Kl[64 * 264];       // rows, pad 256->264
  alignas(16) __shared__ u16 Vl[256 * 72];       // V^T [c][t_local], pad 64->72

  int bid = blockIdx.x;
  int which = blockIdx.y;                        // 0 = K, 1 = V, 2 = Q
  int tid  = threadIdx.x;
  int wave = tid >> 6, lane = tid & 63, quad = lane >> 4, l16 = lane & 15;
  int row0 = bid * 64 + wave * 16;

  s8v a[8];
  const float* xp = x + (size_t)(row0 + l16) * DIM + quad * 8;
  #pragma unroll
  for (int ks = 0; ks < 8; ks++) a[ks] = pack8(xp + ks * 32);

  if (which == 0) {
    const u16* W = Wt + DIM * DIM;               // Wk^T
    f4v acc[16];
    #pragma unroll
    for (int nt = 0; nt < 16; nt++) acc[nt] = (f4v){0.f, 0.f, 0.f, 0.f};
    #pragma unroll
    for (int ks = 0; ks < 8; ks++) {
      #pragma unroll
      for (int nt = 0; nt < 16; nt++) {
        s8v bfr = *(const s8v*)(W + (nt * 16 + l16) * DIM + ks * 32 + quad * 8);
        acc[nt] = MFMA16(a[ks], bfr, acc[nt]);
      }
    }
    #pragma unroll
    for (int nt = 0; nt < 16; nt++) {
      float bb = bk[nt * 16 + l16];
      #pragma unroll
      for (int r = 0; r < 4; r++)
        Kl[(wave * 16 + quad * 4 + r) * 264 + nt * 16 + l16] = f2bf(acc[nt][r] + bb);
    }
    __syncthreads();
    #pragma unroll
    for (int i = 0; i < 8; i++) {                // 2048 chunks, 8/thread
      int o = tid + i * 256;
      int tile = o >> 10, rem = o & 1023;
      int f = rem >> 6, ln = rem & 63;
      int sl = tile * 32 + (f >> 3) * 16 + (ln & 15);
      int c  = (f & 7) * 32 + (ln >> 4) * 8;
      s8v v = *(const s8v*)&Kl[sl * 264 + c];
      *(s8v*)&kf[(((size_t)(bid * 2 + tile) * 16 + f) * 64 + ln) * 8] = v;
    }
  } else if (which == 1) {
    const u16* W = Wt + 2 * DIM * DIM;           // Wv^T
    f4v acc[16];
    #pragma unroll
    for (int nt = 0; nt < 16; nt++) acc[nt] = (f4v){0.f, 0.f, 0.f, 0.f};
    #pragma unroll
    for (int ks = 0; ks < 8; ks++) {
      #pragma unroll
      for (int nt = 0; nt < 16; nt++) {
        s8v bfr = *(const s8v*)(W + (nt * 16 + l16) * DIM + ks * 32 + quad * 8);
        acc[nt] = MFMA16(a[ks], bfr, acc[nt]);
      }
    }
    #pragma unroll
    for (int nt = 0; nt < 16; nt++) {
      float bb = bv[nt * 16 + l16];
      union { u16 h[4]; uint2 v2; } pk;
      #pragma unroll
      for (int r = 0; r < 4; r++) pk.h[r] = f2bf(acc[nt][r] + bb);
      *(uint2*)&Vl[(nt * 16 + l16) * 72 + wave * 16 + quad * 4] = pk.v2;
    }
    __syncthreads();
    #pragma unroll
    for (int i = 0; i < 8; i++) {                // 2048 chunks, 8/thread
      int o = tid + i * 256;
      int tile = o >> 10, rem = o & 1023;
      int nt = rem >> 6, ln = rem & 63;
      int c  = nt * 16 + (ln & 15);
      int sl = tile * 32 + (ln >> 4) * 8;
      s8v v = *(const s8v*)&Vl[c * 72 + sl];
      *(s8v*)&vf[(((size_t)(bid * 2 + tile) * 16 + nt) * 64 + ln) * 8] = v;
    }
  } else {                                       // Q: frag-major like K, pre-scaled
    const u16* W = Wt;                           // Wq^T
    f4v acc[16];
    #pragma unroll
    for (int nt = 0; nt < 16; nt++) acc[nt] = (f4v){0.f, 0.f, 0.f, 0.f};
    #pragma unroll
    for (int ks = 0; ks < 8; ks++) {
      #pragma unroll
      for (int nt = 0; nt < 16; nt++) {
        s8v bfr = *(const s8v*)(W + (nt * 16 + l16) * DIM + ks * 32 + quad * 8);
        acc[nt] = MFMA16(a[ks], bfr, acc[nt]);
      }
    }
    #pragma unroll
    for (int nt = 0; nt < 16; nt++) {
      float bb = bq[nt * 16 + l16];
      #pragma unroll
      for (int r = 0; r < 4; r++)
        Kl[(wave * 16 + quad * 4 + r) * 264 + nt * 16 + l16] =
            f2bf((acc[nt][r] + bb) * 0.0625f);   // pre-scale 1/sqrt(256)
    }
    __syncthreads();
    #pragma unroll
    for (int i = 0; i < 8; i++) {                // 2048 chunks, 8/thread
      int o = tid + i * 256;
      int tile = o >> 10, rem = o & 1023;
      int f = rem >> 6, ln = rem & 63;
      int sl = tile * 32 + (f >> 3) * 16 + (ln & 15);
      int c  = (f & 7) * 32 + (ln >> 4) * 8;
      s8v v = *(const s8v*)&Kl[sl * 264 + c];
      *(s8v*)&qf[(((size_t)(bid * 2 + tile) * 16 + f) * 64 + ln) * 8] = v;
    }
  }
}

// ---------- kernel 3 v10: flash attn, 8-wave blocks, 2 blocks/CU -------------
// r9 DIAGNOSIS: 68us at ~45% LDS BW, Occ 34%, grid 256 = 1 block/CU. A single
// 16-wave gang in lockstep (FENCE+s_barrier+syncthreads per iter) leaves the
// CU idle at every barrier. FIX: 8-wave blocks (4 slabs x 2 halves, 64-row
// q-tiles), grid 512 = 2 INDEPENDENT blocks/CU (LDS 70KB x2 = 140 <= 160) ->
// one block's barrier bubble overlaps the other's MFMA/DMA. Per-row LDS/HBM
// traffic and partial-slot bytes identical to r9.
__global__ __launch_bounds__(512, 4) void attn_kernel(
    const u16* __restrict__ qf, const u16* __restrict__ kf, const u16* __restrict__ vf,
    float* __restrict__ Opart, float* __restrict__ lpart, float* __restrict__ out) {
  alignas(16) __shared__ u16 KVa[16384];          // 32 KB: K 16KB | V 16KB
  alignas(16) __shared__ u16 KVb[16384];          // 32 KB
  alignas(16) __shared__ u16 Ps[4 * 640];         // 5 KB, per-SLAB (2 waves), stride 40
  __shared__ float lbuf[4][2][16];                // per-slab, per-half row sums
  __shared__ int taskS;

  int bid = blockIdx.x, b = bid & 3;              // batch <-> XCD affinity
  int tid = threadIdx.x;
  int w = tid >> 6, lane = tid & 63, quad = lane >> 4, l16 = lane & 15;
  int s = w >> 1, h = w & 1;                      // slab 0..3, kv/col-half 0..1

  const u16* qfb = qf + (size_t)b * 128 * 8192;
  const u16* kfb = kf + (size_t)b * 128 * 8192;
  const u16* vfb = vf + (size_t)b * 128 * 8192;

  for (;;) {
    if (tid == 0) taskS = atomicAdd(&g_cnt[b], 1);
    __syncthreads();                              // also orders prev-task LDS reads
    int t = taskS;
    if (t >= 160) break;
    // size-descending enumeration over (q 64-row tile in 0..63, c 32-kv chunk)
    // 100 full-32 tasks first, then remainders 30,28,...,2 (4 of each).
    int q, c;
    if (t < 48)       { q = 48 + (t & 15); c = t >> 4; }               // c=0,1,2
    else if (t < 80)  { q = 32 + ((t - 48) & 15); c = (t - 48) >> 4; } // c=0,1
    else if (t < 96)  { q = 16 + (t - 80); c = 0; }
    else if (t == 96) { q = 15; c = 0; }
    else if (t == 97) { q = 31; c = 1; }
    else if (t == 98) { q = 47; c = 2; }
    else if (t == 99) { q = 63; c = 3; }
    else { int u = t - 100, sz = u >> 2, band = u & 3;
           if (band == 0)      { q = 14 - sz; c = 0; }
           else if (band == 1) { q = 30 - sz; c = 1; }
           else if (band == 2) { q = 46 - sz; c = 2; }
           else                { q = 62 - sz; c = 3; } }
    int row0 = q * 64;
    int n = 2 * q + 2;                            // causal kv-tile count
    int lo = c * 32, hi = min(n, lo + 32);        // chunk (size even, >= 2)
    int nch = (q >> 4) + 1;                       // chunks for this tile (1..4)

    // ---- Q A-frags -> registers (once per task; frag-major, coalesced) ----
    s8v qa[8];
    {
      const u16* qt = qfb + (((size_t)(q * 2 + (s >> 1)) * 16 + (s & 1) * 8) * 64) * 8;
      #pragma unroll
      for (int ks = 0; ks < 8; ks++) qa[ks] = *(const s8v*)(qt + (ks * 64 + lane) * 8);
    }

    // ---- prologue: DMA first KV tile into KVa (2 K + 2 V chunks per wave) ----
    {
      const u16* kt = kfb + ((size_t)lo << 13);
      const u16* vt = vfb + ((size_t)lo << 13);
      #pragma unroll
      for (int i = 0; i < 2; i++) {
        int ch = (w << 1) + i;                    // 0..15
        gll16(kt + (ch << 9) + (lane << 3), &KVa[ch << 9]);
        gll16(vt + (ch << 9) + (lane << 3), &KVa[8192 + (ch << 9)]);
      }
    }
    __syncthreads();                              // drains DMA

    int rowBase = row0 + (s << 4);
    f4v o[8];
    #pragma unroll
    for (int nt = 0; nt < 8; nt++) o[nt] = (f4v){0.f, 0.f, 0.f, 0.f};
    float lrow[4] = {0.f, 0.f, 0.f, 0.f};

    auto iter_body = [&](const u16* buf, int kvi) {
      // S half: wave h computes S for its slab x 16 kv cols (h*16..h*16+15)
      f4v cc = (f4v){0.f, 0.f, 0.f, 0.f};
      #pragma unroll
      for (int ks = 0; ks < 8; ks++) {
        s8v kfr = *(const s8v*)&buf[(((h << 3) + ks) << 9) + (lane << 3)];
        cc = MFMA16(qa[ks], kfr, cc);
      }
      int s0 = kvi * 32 + (h << 4) + l16;
      #pragma unroll
      for (int r = 0; r < 4; r++) {
        int tq = rowBase + (quad << 2) + r;
        float p = __expf((s0 > tq) ? -1e30f : cc[r]);
        Ps[s * 640 + ((quad << 2) + r) * 40 + (h << 4) + l16] = f2bf(p);
        lrow[r] += p;
      }
      // P exchange: own writes drained (lgkm), partner sync via RAW s_barrier
      // (no vmcnt drain -> next-tile DMA stays in flight across it).
      FENCE_LGKM();
      __builtin_amdgcn_sched_barrier(0);
      __builtin_amdgcn_s_barrier();
      __builtin_amdgcn_sched_barrier(0);
      s8v pa = *(const s8v*)&Ps[s * 640 + l16 * 40 + (quad << 3)];
      #pragma unroll
      for (int nt = 0; nt < 8; nt++) {
        s8v vfr = *(const s8v*)&buf[8192 + (((h << 3) + nt) << 9) + (lane << 3)];
        o[nt] = MFMA16(pa, vfr, o[nt]);
      }
    };

    #pragma unroll 1
    for (int kv = lo; kv < hi; kv += 2) {
      {                                           // prefetch kv+1 -> KVb (always valid)
        const u16* kt = kfb + ((size_t)(kv + 1) << 13);
        const u16* vt = vfb + ((size_t)(kv + 1) << 13);
        #pragma unroll
        for (int i = 0; i < 2; i++) {
          int ch = (w << 1) + i;
          gll16(kt + (ch << 9) + (lane << 3), &KVb[ch << 9]);
          gll16(vt + (ch << 9) + (lane << 3), &KVb[8192 + (ch << 9)]);
        }
      }
      iter_body(KVa, kv);
      __syncthreads();                            // KVb ready, KVa free, Ps consumed
      if (kv + 2 < hi) {                          // prefetch kv+2 -> KVa
        const u16* kt = kfb + ((size_t)(kv + 2) << 13);
        const u16* vt = vfb + ((size_t)(kv + 2) << 13);
        #pragma unroll
        for (int i = 0; i < 2; i++) {
          int ch = (w << 1) + i;
          gll16(kt + (ch << 9) + (lane << 3), &KVa[ch << 9]);
          gll16(vt + (ch << 9) + (lane << 3), &KVa[8192 + (ch << 9)]);
        }
      }
      iter_body(KVb, kv + 1);
      __syncthreads();                            // KVa ready, KVb free
    }

    // ---- epilogue: per-half row sums -> combine across halves via lbuf ----
    #pragma unroll
    for (int r = 0; r < 4; r++) {
      #pragma unroll
      for (int d = 1; d < 16; d <<= 1) lrow[r] += __shfl_xor(lrow[r], d);
    }
    if (l16 == 0) {
      #pragma unroll
      for (int r = 0; r < 4; r++) lbuf[s][h][(quad << 2) + r] = lrow[r];
    }
    __syncthreads();                              // lbuf ready for both halves

    if (nch == 1) {                               // whole kv range done: store
      #pragma unroll
      for (int nt = 0; nt < 8; nt++) {
        #pragma unroll
        for (int r = 0; r < 4; r++) {
          float ls = lbuf[s][0][(quad << 2) + r] + lbuf[s][1][(quad << 2) + r];
          out[(size_t)(b * T_SEQ + rowBase + (quad << 2) + r) * DIM +
              ((h * 8 + nt) * 16 + l16)] = o[nt][r] / ls;
        }
      }
    } else {                                      // fp32 partial to compact slot
      int slotB = (q < 32) ? (q - 16) * 2
                : (q < 48) ? 32 + (q - 32) * 3
                           : 80 + (q - 48) * 4;
      int slot = b * 144 + slotB + c;
      float* Op = Opart + ((size_t)slot << 14);   // 64*256 floats per slot
      #pragma unroll
      for (int nt = 0; nt < 8; nt++) {
        #pragma unroll
        for (int r = 0; r < 4; r++)
          Op[((s << 4) + (quad << 2) + r) * 256 + (h * 8 + nt) * 16 + l16] = o[nt][r];
      }
      if (h == 0 && l16 == 0) {
        #pragma unroll
        for (int r = 0; r < 4; r++)
          lpart[slot * 64 + (s << 4) + (quad << 2) + r] =
              lbuf[s][0][(quad << 2) + r] + lbuf[s][1][(quad << 2) + r];
      }
    }
  }
}

// ---------- kernel 4: combine partials for multi-chunk tiles (q >= 16) -----
// grid 768 = 4 b x 48 q x 4 row-groups; block 256 (thread = column).
__global__ void combine_kernel(const float* __restrict__ Opart,
                               const float* __restrict__ lpart,
                               float* __restrict__ out) {
  int blk = blockIdx.x;
  int b = blk & 3;
  int rest = blk >> 2;                            // 0..191
  int q = 16 + (rest >> 2);                       // 16..63
  int g = rest & 3;                               // 16-row group
  int col = threadIdx.x;
  int nch = (q >> 4) + 1;                         // 2,3,4
  int slotB = (q < 32) ? (q - 16) * 2
            : (q < 48) ? 32 + (q - 32) * 3
                       : 80 + (q - 48) * 4;
  int slot0 = b * 144 + slotB;
  #pragma unroll 4
  for (int i = 0; i < 16; i++) {
    int rt = g * 16 + i;                          // row within 64-row tile
    float acc = 0.f, ls = 0.f;
    for (int c = 0; c < nch; c++) {
      acc += Opart[(((size_t)(slot0 + c)) << 14) + rt * 256 + col];
      ls  += lpart[(slot0 + c) * 64 + rt];
    }
    out[(size_t)(b * T_SEQ + q * 64 + rt) * DIM + col] = acc / ls;
  }
}

extern "C" void kernel_launch(void* const* d_in, const int* in_sizes, int n_in,
                              void* d_out, int out_size, void* d_ws, size_t ws_size,
                              hipStream_t stream) {
  const float* x  = (const float*)d_in[0];
  const float* Wq = (const float*)d_in[1];
  const float* bq = (const float*)d_in[2];
  const float* Wk = (const float*)d_in[3];
  const float* bk = (const float*)d_in[4];
  const float* Wv = (const float*)d_in[5];
  const float* bv = (const float*)d_in[6];

  const size_t NTD = (size_t)NBATCH * T_SEQ * DIM;             // 4,194,304 elems
  const size_t WT_ELEMS = (size_t)3 * DIM * DIM;               //   196,608 elems
  const size_t NSLOT = 576;                                    // partial slots (64x256)
  const size_t REQ_BYTES = (WT_ELEMS + 3 * NTD) * sizeof(u16)  // 25,559,040
                         + NSLOT * 16384 * sizeof(float)       // 37,748,736 Opart
                         + NSLOT * 64 * sizeof(float);         //    147,456 lpart

  if (ws_size < REQ_BYTES) {
    float val = (float)(ws_size >> 20);   // diagnostic: absmax encodes ws MiB
    diag_fill_kernel<<<(out_size + 255) / 256, 256, 0, stream>>>((float*)d_out, val, out_size);
    return;
  }

  u16* ws = (u16*)d_ws;
  u16* WT = ws;                    // [0]=Wq^T [1]=Wk^T [2]=Wv^T, 384 KiB
  u16* Kf = ws + WT_ELEMS;         // 8 MiB, frag-major K tiles
  u16* Vf = Kf + NTD;              // 8 MiB, frag-major V^T tiles
  u16* Qf = Vf + NTD;              // 8 MiB, frag-major Q tiles (pre-scaled)
  float* Opart = (float*)(Qf + NTD);               // 36 MiB fp32 partial O
  float* lpart = Opart + NSLOT * 16384;            // 144 KiB fp32 partial l

  wtrans_kernel<<<dim3(8, 8, 3), dim3(32, 8, 1), 0, stream>>>(Wq, Wk, Wv, WT);
  proj_kernel<<<dim3(256, 3, 1), dim3(256, 1, 1), 0, stream>>>(x, WT, bq, bk, bv, Qf, Kf, Vf);
  attn_kernel<<<dim3(512, 1, 1), dim3(512, 1, 1), 0, stream>>>(Qf, Kf, Vf,
                                                               Opart, lpart, (float*)d_out);
  combine_kernel<<<dim3(768, 1, 1), dim3(256, 1, 1), 0, stream>>>(Opart, lpart, (float*)d_out);
}